// Round 1
// baseline (869.056 us; speedup 1.0000x reference)
//
#include <hip/hip_runtime.h>

#define DD 64

__global__ void zero_int_kernel(int* p, int n) {
    int i = blockIdx.x * blockDim.x + threadIdx.x;
    if (i < n) p[i] = 0;
}

__global__ void count_deg_kernel(const int* __restrict__ dst, int e, int* __restrict__ deg) {
    int i = blockIdx.x * blockDim.x + threadIdx.x;
    if (i < e) atomicAdd(&deg[dst[i]], 1);
}

// Single-block exclusive scan over deg[0..n) -> rowp[0..n], also copies to cursor.
__global__ void scan_kernel(const int* __restrict__ deg, int n,
                            int* __restrict__ rowp, int* __restrict__ cursor) {
    __shared__ int part[1024];
    int tid = threadIdx.x;
    int per = (n + 1023) >> 10;
    int s0 = tid * per;
    int s1 = s0 + per; if (s1 > n) s1 = n;
    int s = 0;
    for (int i = s0; i < s1; ++i) s += deg[i];
    part[tid] = s;
    __syncthreads();
    // Hillis-Steele inclusive scan of per-thread sums
    for (int off = 1; off < 1024; off <<= 1) {
        int v = (tid >= off) ? part[tid - off] : 0;
        __syncthreads();
        part[tid] += v;
        __syncthreads();
    }
    int run = part[tid] - s;   // exclusive prefix for this thread's chunk
    for (int i = s0; i < s1; ++i) {
        rowp[i] = run;
        cursor[i] = run;
        run += deg[i];
    }
    if (tid == 1023) rowp[n] = part[1023];
}

__global__ void fill_kernel(const int* __restrict__ src, const int* __restrict__ dst, int e,
                            int* __restrict__ cursor, int* __restrict__ esrc) {
    int i = blockIdx.x * blockDim.x + threadIdx.x;
    if (i < e) {
        int p = atomicAdd(&cursor[dst[i]], 1);
        esrc[p] = src[i];
    }
}

// Fused: per node, mean-aggregate incoming src rows (CSR) then
// hout = agg @ Wl + hin @ Wr + b (+ optional relu).
// 16 lanes per node, each lane owns 4 output columns (float4).
__global__ __launch_bounds__(256) void sage_layer_kernel(
    const float* __restrict__ hin, const int* __restrict__ rowp,
    const int* __restrict__ esrc,
    const float* __restrict__ Wl, const float* __restrict__ Wr,
    const float* __restrict__ bias, float* __restrict__ hout,
    int n, int relu)
{
    __shared__ float sWl[DD * DD];   // 16 KB
    __shared__ float sWr[DD * DD];   // 16 KB
    __shared__ float sB[DD];
    __shared__ float sAgg[16][68];   // stride 68 floats: keeps 16B align, spreads banks
    __shared__ float sH[16][68];

    int tid = threadIdx.x;
    // stage weights (vectorized)
    for (int i = tid; i < DD * DD / 4; i += 256) {
        reinterpret_cast<float4*>(sWl)[i] = reinterpret_cast<const float4*>(Wl)[i];
        reinterpret_cast<float4*>(sWr)[i] = reinterpret_cast<const float4*>(Wr)[i];
    }
    if (tid < DD) sB[tid] = bias[tid];
    __syncthreads();

    int grp = tid >> 4;      // node within block (0..15)
    int l   = tid & 15;      // lane within node
    int node = blockIdx.x * 16 + grp;
    if (node >= n) return;

    int beg = rowp[node], end = rowp[node + 1];
    float ax = 0.f, ay = 0.f, az = 0.f, aw = 0.f;
    for (int t = beg; t < end; ++t) {
        int s = esrc[t];
        float4 v = *reinterpret_cast<const float4*>(hin + (size_t)s * DD + l * 4);
        ax += v.x; ay += v.y; az += v.z; aw += v.w;
    }
    float cnt = fmaxf((float)(end - beg), 1.0f);
    ax /= cnt; ay /= cnt; az /= cnt; aw /= cnt;

    float4 h4 = *reinterpret_cast<const float4*>(hin + (size_t)node * DD + l * 4);
    // wave-internal LDS exchange (16 writer lanes == 16 reader lanes, same wave)
    *reinterpret_cast<float4*>(&sAgg[grp][l * 4]) = make_float4(ax, ay, az, aw);
    *reinterpret_cast<float4*>(&sH[grp][l * 4])   = h4;

    float o0 = sB[l * 4 + 0], o1 = sB[l * 4 + 1], o2 = sB[l * 4 + 2], o3 = sB[l * 4 + 3];
#pragma unroll 8
    for (int k = 0; k < DD; ++k) {
        float a = sAgg[grp][k];
        float h = sH[grp][k];
        float4 wl = *reinterpret_cast<const float4*>(&sWl[k * DD + l * 4]);
        float4 wr = *reinterpret_cast<const float4*>(&sWr[k * DD + l * 4]);
        o0 += a * wl.x + h * wr.x;
        o1 += a * wl.y + h * wr.y;
        o2 += a * wl.z + h * wr.z;
        o3 += a * wl.w + h * wr.w;
    }
    if (relu) {
        o0 = fmaxf(o0, 0.f); o1 = fmaxf(o1, 0.f);
        o2 = fmaxf(o2, 0.f); o3 = fmaxf(o3, 0.f);
    }
    *reinterpret_cast<float4*>(hout + (size_t)node * DD + l * 4) = make_float4(o0, o1, o2, o3);
}

extern "C" void kernel_launch(void* const* d_in, const int* in_sizes, int n_in,
                              void* d_out, int out_size, void* d_ws, size_t ws_size,
                              hipStream_t stream) {
    (void)n_in; (void)out_size; (void)ws_size;
    const float* x  = (const float*)d_in[0];
    const int*   ei = (const int*)d_in[1];
    const float* Wl = (const float*)d_in[2];
    const float* Wr = (const float*)d_in[3];
    const float* bb = (const float*)d_in[4];
    float* out = (float*)d_out;

    int n = in_sizes[0] / DD;   // 100000
    int e = in_sizes[1] / 2;    // 1600000
    const int* src = ei;
    const int* dst = ei + e;

    char* cur = (char*)d_ws;
    auto alloc = [&](size_t bytes) -> void* {
        void* p = (void*)cur;
        cur += (bytes + 255) & ~(size_t)255;
        return p;
    };
    int*   deg    = (int*)alloc((size_t)n * 4);
    int*   rowp   = (int*)alloc(((size_t)n + 1) * 4);
    int*   cursor = (int*)alloc((size_t)n * 4);
    int*   esrc   = (int*)alloc((size_t)e * 4);
    float* hA     = (float*)alloc((size_t)n * DD * 4);
    float* hB     = (float*)alloc((size_t)n * DD * 4);

    // Build CSR (by dst) once per call
    zero_int_kernel<<<(n + 255) / 256, 256, 0, stream>>>(deg, n);
    count_deg_kernel<<<(e + 255) / 256, 256, 0, stream>>>(dst, e, deg);
    scan_kernel<<<1, 1024, 0, stream>>>(deg, n, rowp, cursor);
    fill_kernel<<<(e + 255) / 256, 256, 0, stream>>>(src, dst, e, cursor, esrc);

    int lb = (n + 15) / 16;
    sage_layer_kernel<<<lb, 256, 0, stream>>>(x,  rowp, esrc, Wl,            Wr,            bb,          hA,  n, 1);
    sage_layer_kernel<<<lb, 256, 0, stream>>>(hA, rowp, esrc, Wl + 4096,     Wr + 4096,     bb + DD,     hB,  n, 1);
    sage_layer_kernel<<<lb, 256, 0, stream>>>(hB, rowp, esrc, Wl + 2 * 4096, Wr + 2 * 4096, bb + 2 * DD, out, n, 0);
}

// Round 2
// 653.847 us; speedup vs baseline: 1.3291x; 1.3291x over previous
//
#include <hip/hip_runtime.h>

#define DD 64
#define CHUNK 1024   // elements per scan block (256 threads x 4)

__global__ void zero_int_kernel(int* p, int n) {
    int i = blockIdx.x * blockDim.x + threadIdx.x;
    if (i < n) p[i] = 0;
}

__global__ void count_deg_kernel(const int* __restrict__ dst, int e, int* __restrict__ deg) {
    int i = blockIdx.x * blockDim.x + threadIdx.x;
    if (i < e) atomicAdd(&deg[dst[i]], 1);
}

// ---- two-level scan: partials -> scan partials -> local scan + write ----

__global__ __launch_bounds__(256) void partial_sum_kernel(const int* __restrict__ deg, int n,
                                                          int* __restrict__ blocksum) {
    __shared__ int red[256];
    int tid = threadIdx.x;
    int base = blockIdx.x * CHUNK + tid * 4;
    int s = 0;
#pragma unroll
    for (int j = 0; j < 4; ++j) {
        int i = base + j;
        if (i < n) s += deg[i];
    }
    red[tid] = s;
    __syncthreads();
    for (int off = 128; off > 0; off >>= 1) {
        if (tid < off) red[tid] += red[tid + off];
        __syncthreads();
    }
    if (tid == 0) blocksum[blockIdx.x] = red[0];
}

// single block, 1024 threads; nblocks <= 1024
__global__ __launch_bounds__(1024) void scan_partials_kernel(int* __restrict__ blocksum, int nblocks,
                                                             int* __restrict__ blockoff,
                                                             int* __restrict__ rowp_last, int n) {
    __shared__ int sc[1024];
    int tid = threadIdx.x;
    int v = (tid < nblocks) ? blocksum[tid] : 0;
    sc[tid] = v;
    __syncthreads();
    for (int off = 1; off < 1024; off <<= 1) {
        int t = (tid >= off) ? sc[tid - off] : 0;
        __syncthreads();
        sc[tid] += t;
        __syncthreads();
    }
    if (tid < nblocks) blockoff[tid] = sc[tid] - v;   // exclusive
    if (tid == 1023) rowp_last[n] = sc[1023];         // total edges
}

__global__ __launch_bounds__(256) void write_scan_kernel(const int* __restrict__ deg, int n,
                                                         const int* __restrict__ blockoff,
                                                         int* __restrict__ rowp, int* __restrict__ cursor) {
    __shared__ int sc[256];
    int tid = threadIdx.x;
    int base = blockIdx.x * CHUNK + tid * 4;
    int e0 = 0, e1 = 0, e2 = 0, e3 = 0;
    if (base + 0 < n) e0 = deg[base + 0];
    if (base + 1 < n) e1 = deg[base + 1];
    if (base + 2 < n) e2 = deg[base + 2];
    if (base + 3 < n) e3 = deg[base + 3];
    int s = e0 + e1 + e2 + e3;
    sc[tid] = s;
    __syncthreads();
    for (int off = 1; off < 256; off <<= 1) {
        int t = (tid >= off) ? sc[tid - off] : 0;
        __syncthreads();
        sc[tid] += t;
        __syncthreads();
    }
    int run = blockoff[blockIdx.x] + sc[tid] - s;   // exclusive prefix for this thread
    int p0 = run, p1 = run + e0, p2 = p1 + e1, p3 = p2 + e2;
    if (base + 0 < n) { rowp[base + 0] = p0; cursor[base + 0] = p0; }
    if (base + 1 < n) { rowp[base + 1] = p1; cursor[base + 1] = p1; }
    if (base + 2 < n) { rowp[base + 2] = p2; cursor[base + 2] = p2; }
    if (base + 3 < n) { rowp[base + 3] = p3; cursor[base + 3] = p3; }
}

__global__ void fill_kernel(const int* __restrict__ src, const int* __restrict__ dst, int e,
                            int* __restrict__ cursor, int* __restrict__ esrc) {
    int i = blockIdx.x * blockDim.x + threadIdx.x;
    if (i < e) {
        int p = atomicAdd(&cursor[dst[i]], 1);
        esrc[p] = src[i];
    }
}

// Fused: per node, mean-aggregate incoming src rows (CSR) then
// hout = agg @ Wl + hin @ Wr + b (+ optional relu).
// 16 lanes per node, each lane owns 4 output columns (float4).
__global__ __launch_bounds__(256) void sage_layer_kernel(
    const float* __restrict__ hin, const int* __restrict__ rowp,
    const int* __restrict__ esrc,
    const float* __restrict__ Wl, const float* __restrict__ Wr,
    const float* __restrict__ bias, float* __restrict__ hout,
    int n, int relu)
{
    __shared__ float sWl[DD * DD];   // 16 KB
    __shared__ float sWr[DD * DD];   // 16 KB
    __shared__ float sB[DD];
    __shared__ float sAgg[16][68];
    __shared__ float sH[16][68];

    int tid = threadIdx.x;
    for (int i = tid; i < DD * DD / 4; i += 256) {
        reinterpret_cast<float4*>(sWl)[i] = reinterpret_cast<const float4*>(Wl)[i];
        reinterpret_cast<float4*>(sWr)[i] = reinterpret_cast<const float4*>(Wr)[i];
    }
    if (tid < DD) sB[tid] = bias[tid];
    __syncthreads();

    int grp = tid >> 4;      // node within block (0..15)
    int l   = tid & 15;      // lane within node
    int node = blockIdx.x * 16 + grp;
    if (node >= n) return;

    int beg = rowp[node], end = rowp[node + 1];
    float ax = 0.f, ay = 0.f, az = 0.f, aw = 0.f;
    for (int t = beg; t < end; ++t) {
        int s = esrc[t];
        float4 v = *reinterpret_cast<const float4*>(hin + (size_t)s * DD + l * 4);
        ax += v.x; ay += v.y; az += v.z; aw += v.w;
    }
    float cnt = fmaxf((float)(end - beg), 1.0f);
    ax /= cnt; ay /= cnt; az /= cnt; aw /= cnt;

    float4 h4 = *reinterpret_cast<const float4*>(hin + (size_t)node * DD + l * 4);
    *reinterpret_cast<float4*>(&sAgg[grp][l * 4]) = make_float4(ax, ay, az, aw);
    *reinterpret_cast<float4*>(&sH[grp][l * 4])   = h4;

    float o0 = sB[l * 4 + 0], o1 = sB[l * 4 + 1], o2 = sB[l * 4 + 2], o3 = sB[l * 4 + 3];
#pragma unroll 8
    for (int k = 0; k < DD; ++k) {
        float a = sAgg[grp][k];
        float h = sH[grp][k];
        float4 wl = *reinterpret_cast<const float4*>(&sWl[k * DD + l * 4]);
        float4 wr = *reinterpret_cast<const float4*>(&sWr[k * DD + l * 4]);
        o0 += a * wl.x + h * wr.x;
        o1 += a * wl.y + h * wr.y;
        o2 += a * wl.z + h * wr.z;
        o3 += a * wl.w + h * wr.w;
    }
    if (relu) {
        o0 = fmaxf(o0, 0.f); o1 = fmaxf(o1, 0.f);
        o2 = fmaxf(o2, 0.f); o3 = fmaxf(o3, 0.f);
    }
    *reinterpret_cast<float4*>(hout + (size_t)node * DD + l * 4) = make_float4(o0, o1, o2, o3);
}

extern "C" void kernel_launch(void* const* d_in, const int* in_sizes, int n_in,
                              void* d_out, int out_size, void* d_ws, size_t ws_size,
                              hipStream_t stream) {
    (void)n_in; (void)out_size; (void)ws_size;
    const float* x  = (const float*)d_in[0];
    const int*   ei = (const int*)d_in[1];
    const float* Wl = (const float*)d_in[2];
    const float* Wr = (const float*)d_in[3];
    const float* bb = (const float*)d_in[4];
    float* out = (float*)d_out;

    int n = in_sizes[0] / DD;   // 100000
    int e = in_sizes[1] / 2;    // 1600000
    const int* src = ei;
    const int* dst = ei + e;

    char* cur = (char*)d_ws;
    auto alloc = [&](size_t bytes) -> void* {
        void* p = (void*)cur;
        cur += (bytes + 255) & ~(size_t)255;
        return p;
    };
    int*   deg      = (int*)alloc((size_t)n * 4);
    int*   rowp     = (int*)alloc(((size_t)n + 1) * 4);
    int*   cursor   = (int*)alloc((size_t)n * 4);
    int*   esrc     = (int*)alloc((size_t)e * 4);
    int*   blocksum = (int*)alloc(1024 * 4);
    int*   blockoff = (int*)alloc(1024 * 4);
    float* hA       = (float*)alloc((size_t)n * DD * 4);
    float* hB       = (float*)alloc((size_t)n * DD * 4);

    int nblocks = (n + CHUNK - 1) / CHUNK;   // 98

    zero_int_kernel<<<(n + 255) / 256, 256, 0, stream>>>(deg, n);
    count_deg_kernel<<<(e + 255) / 256, 256, 0, stream>>>(dst, e, deg);
    partial_sum_kernel<<<nblocks, 256, 0, stream>>>(deg, n, blocksum);
    scan_partials_kernel<<<1, 1024, 0, stream>>>(blocksum, nblocks, blockoff, rowp, n);
    write_scan_kernel<<<nblocks, 256, 0, stream>>>(deg, n, blockoff, rowp, cursor);
    fill_kernel<<<(e + 255) / 256, 256, 0, stream>>>(src, dst, e, cursor, esrc);

    int lb = (n + 15) / 16;
    sage_layer_kernel<<<lb, 256, 0, stream>>>(x,  rowp, esrc, Wl,            Wr,            bb,          hA,  n, 1);
    sage_layer_kernel<<<lb, 256, 0, stream>>>(hA, rowp, esrc, Wl + 4096,     Wr + 4096,     bb + DD,     hB,  n, 1);
    sage_layer_kernel<<<lb, 256, 0, stream>>>(hB, rowp, esrc, Wl + 2 * 4096, Wr + 2 * 4096, bb + 2 * DD, out, n, 0);
}

// Round 3
// 440.740 us; speedup vs baseline: 1.9718x; 1.4835x over previous
//
#include <hip/hip_runtime.h>

#define DD 64
#define CHUNK 1024   // elements per scan block (256 threads x 4)
#define NPB 32       // nodes per block in sage_layer (512 threads, 16 lanes/node)

__global__ void zero_int_kernel(int* p, int n) {
    int i = blockIdx.x * blockDim.x + threadIdx.x;
    if (i < n) p[i] = 0;
}

__global__ void count_deg_kernel(const int* __restrict__ dst, int e, int* __restrict__ deg) {
    int i = (blockIdx.x * blockDim.x + threadIdx.x) * 4;
    if (i + 4 <= e) {
        int4 d = *reinterpret_cast<const int4*>(dst + i);
        atomicAdd(&deg[d.x], 1);
        atomicAdd(&deg[d.y], 1);
        atomicAdd(&deg[d.z], 1);
        atomicAdd(&deg[d.w], 1);
    } else {
        for (; i < e; ++i) atomicAdd(&deg[dst[i]], 1);
    }
}

// ---- two-level scan: partials -> scan partials -> local scan + write ----

__global__ __launch_bounds__(256) void partial_sum_kernel(const int* __restrict__ deg, int n,
                                                          int* __restrict__ blocksum) {
    __shared__ int red[256];
    int tid = threadIdx.x;
    int base = blockIdx.x * CHUNK + tid * 4;
    int s = 0;
#pragma unroll
    for (int j = 0; j < 4; ++j) {
        int i = base + j;
        if (i < n) s += deg[i];
    }
    red[tid] = s;
    __syncthreads();
    for (int off = 128; off > 0; off >>= 1) {
        if (tid < off) red[tid] += red[tid + off];
        __syncthreads();
    }
    if (tid == 0) blocksum[blockIdx.x] = red[0];
}

__global__ __launch_bounds__(1024) void scan_partials_kernel(int* __restrict__ blocksum, int nblocks,
                                                             int* __restrict__ blockoff,
                                                             int* __restrict__ rowp_last, int n) {
    __shared__ int sc[1024];
    int tid = threadIdx.x;
    int v = (tid < nblocks) ? blocksum[tid] : 0;
    sc[tid] = v;
    __syncthreads();
    for (int off = 1; off < 1024; off <<= 1) {
        int t = (tid >= off) ? sc[tid - off] : 0;
        __syncthreads();
        sc[tid] += t;
        __syncthreads();
    }
    if (tid < nblocks) blockoff[tid] = sc[tid] - v;   // exclusive
    if (tid == 1023) rowp_last[n] = sc[1023];         // total edges
}

__global__ __launch_bounds__(256) void write_scan_kernel(const int* __restrict__ deg, int n,
                                                         const int* __restrict__ blockoff,
                                                         int* __restrict__ rowp, int* __restrict__ cursor) {
    __shared__ int sc[256];
    int tid = threadIdx.x;
    int base = blockIdx.x * CHUNK + tid * 4;
    int e0 = 0, e1 = 0, e2 = 0, e3 = 0;
    if (base + 0 < n) e0 = deg[base + 0];
    if (base + 1 < n) e1 = deg[base + 1];
    if (base + 2 < n) e2 = deg[base + 2];
    if (base + 3 < n) e3 = deg[base + 3];
    int s = e0 + e1 + e2 + e3;
    sc[tid] = s;
    __syncthreads();
    for (int off = 1; off < 256; off <<= 1) {
        int t = (tid >= off) ? sc[tid - off] : 0;
        __syncthreads();
        sc[tid] += t;
        __syncthreads();
    }
    int run = blockoff[blockIdx.x] + sc[tid] - s;
    int p0 = run, p1 = run + e0, p2 = p1 + e1, p3 = p2 + e2;
    if (base + 0 < n) { rowp[base + 0] = p0; cursor[base + 0] = p0; }
    if (base + 1 < n) { rowp[base + 1] = p1; cursor[base + 1] = p1; }
    if (base + 2 < n) { rowp[base + 2] = p2; cursor[base + 2] = p2; }
    if (base + 3 < n) { rowp[base + 3] = p3; cursor[base + 3] = p3; }
}

__global__ void fill_kernel(const int* __restrict__ src, const int* __restrict__ dst, int e,
                            int* __restrict__ cursor, int* __restrict__ esrc) {
    int i = (blockIdx.x * blockDim.x + threadIdx.x) * 4;
    if (i + 4 <= e) {
        int4 s = *reinterpret_cast<const int4*>(src + i);
        int4 d = *reinterpret_cast<const int4*>(dst + i);
        int p0 = atomicAdd(&cursor[d.x], 1); esrc[p0] = s.x;
        int p1 = atomicAdd(&cursor[d.y], 1); esrc[p1] = s.y;
        int p2 = atomicAdd(&cursor[d.z], 1); esrc[p2] = s.z;
        int p3 = atomicAdd(&cursor[d.w], 1); esrc[p3] = s.w;
    } else {
        for (; i < e; ++i) {
            int p = atomicAdd(&cursor[dst[i]], 1);
            esrc[p] = src[i];
        }
    }
}

// Fused layer: mean-aggregate (CSR gather, 4-deep MLP) then
// hout = agg @ Wl + hin @ Wr + b (+ optional relu).
// 512 threads = 32 nodes/block, 16 lanes/node, lane owns 4 output cols.
__global__ __launch_bounds__(512) void sage_layer_kernel(
    const float* __restrict__ hin, const int* __restrict__ rowp,
    const int* __restrict__ esrc,
    const float* __restrict__ Wl, const float* __restrict__ Wr,
    const float* __restrict__ bias, float* __restrict__ hout,
    int n, int relu)
{
    __shared__ float sWl[DD * DD];     // 16 KB
    __shared__ float sWr[DD * DD];     // 16 KB
    __shared__ float sB[DD];
    __shared__ float sAgg[NPB][68];    // 8.5 KB, +4 pad floats
    __shared__ float sH[NPB][68];

    int tid = threadIdx.x;
    for (int i = tid; i < DD * DD / 4; i += 512) {
        reinterpret_cast<float4*>(sWl)[i] = reinterpret_cast<const float4*>(Wl)[i];
        reinterpret_cast<float4*>(sWr)[i] = reinterpret_cast<const float4*>(Wr)[i];
    }
    if (tid < DD) sB[tid] = bias[tid];
    __syncthreads();

    int grp = tid >> 4;      // node within block (0..31)
    int l   = tid & 15;      // lane within node
    int node = blockIdx.x * NPB + grp;
    if (node >= n) return;

    int beg = rowp[node], end = rowp[node + 1];
    float ax = 0.f, ay = 0.f, az = 0.f, aw = 0.f;
    int t = beg;
    // 4-deep unrolled gather: 4 independent 256B row loads in flight per group
    for (; t + 4 <= end; t += 4) {
        int s0 = esrc[t + 0], s1 = esrc[t + 1], s2 = esrc[t + 2], s3 = esrc[t + 3];
        float4 v0 = *reinterpret_cast<const float4*>(hin + (size_t)s0 * DD + l * 4);
        float4 v1 = *reinterpret_cast<const float4*>(hin + (size_t)s1 * DD + l * 4);
        float4 v2 = *reinterpret_cast<const float4*>(hin + (size_t)s2 * DD + l * 4);
        float4 v3 = *reinterpret_cast<const float4*>(hin + (size_t)s3 * DD + l * 4);
        ax += (v0.x + v1.x) + (v2.x + v3.x);
        ay += (v0.y + v1.y) + (v2.y + v3.y);
        az += (v0.z + v1.z) + (v2.z + v3.z);
        aw += (v0.w + v1.w) + (v2.w + v3.w);
    }
    for (; t < end; ++t) {
        int s = esrc[t];
        float4 v = *reinterpret_cast<const float4*>(hin + (size_t)s * DD + l * 4);
        ax += v.x; ay += v.y; az += v.z; aw += v.w;
    }
    float cnt = fmaxf((float)(end - beg), 1.0f);
    ax /= cnt; ay /= cnt; az /= cnt; aw /= cnt;

    float4 h4 = *reinterpret_cast<const float4*>(hin + (size_t)node * DD + l * 4);
    // wave-internal LDS exchange (16 writer lanes == 16 reader lanes, same wave)
    *reinterpret_cast<float4*>(&sAgg[grp][l * 4]) = make_float4(ax, ay, az, aw);
    *reinterpret_cast<float4*>(&sH[grp][l * 4])   = h4;

    float o0 = sB[l * 4 + 0], o1 = sB[l * 4 + 1], o2 = sB[l * 4 + 2], o3 = sB[l * 4 + 3];
#pragma unroll 8
    for (int k = 0; k < DD; ++k) {
        float a = sAgg[grp][k];
        float h = sH[grp][k];
        float4 wl = *reinterpret_cast<const float4*>(&sWl[k * DD + l * 4]);
        float4 wr = *reinterpret_cast<const float4*>(&sWr[k * DD + l * 4]);
        o0 += a * wl.x + h * wr.x;
        o1 += a * wl.y + h * wr.y;
        o2 += a * wl.z + h * wr.z;
        o3 += a * wl.w + h * wr.w;
    }
    if (relu) {
        o0 = fmaxf(o0, 0.f); o1 = fmaxf(o1, 0.f);
        o2 = fmaxf(o2, 0.f); o3 = fmaxf(o3, 0.f);
    }
    *reinterpret_cast<float4*>(hout + (size_t)node * DD + l * 4) = make_float4(o0, o1, o2, o3);
}

extern "C" void kernel_launch(void* const* d_in, const int* in_sizes, int n_in,
                              void* d_out, int out_size, void* d_ws, size_t ws_size,
                              hipStream_t stream) {
    (void)n_in; (void)out_size; (void)ws_size;
    const float* x  = (const float*)d_in[0];
    const int*   ei = (const int*)d_in[1];
    const float* Wl = (const float*)d_in[2];
    const float* Wr = (const float*)d_in[3];
    const float* bb = (const float*)d_in[4];
    float* out = (float*)d_out;

    int n = in_sizes[0] / DD;   // 100000
    int e = in_sizes[1] / 2;    // 1600000
    const int* src = ei;
    const int* dst = ei + e;

    char* cur = (char*)d_ws;
    auto alloc = [&](size_t bytes) -> void* {
        void* p = (void*)cur;
        cur += (bytes + 255) & ~(size_t)255;
        return p;
    };
    int*   deg      = (int*)alloc((size_t)n * 4);
    int*   rowp     = (int*)alloc(((size_t)n + 1) * 4);
    int*   cursor   = (int*)alloc((size_t)n * 4);
    int*   esrc     = (int*)alloc((size_t)e * 4);
    int*   blocksum = (int*)alloc(1024 * 4);
    int*   blockoff = (int*)alloc(1024 * 4);
    float* hA       = (float*)alloc((size_t)n * DD * 4);
    float* hB       = (float*)alloc((size_t)n * DD * 4);

    int nblocks = (n + CHUNK - 1) / CHUNK;   // 98

    zero_int_kernel<<<(n + 255) / 256, 256, 0, stream>>>(deg, n);
    count_deg_kernel<<<(e / 4 + 255) / 256, 256, 0, stream>>>(dst, e, deg);
    partial_sum_kernel<<<nblocks, 256, 0, stream>>>(deg, n, blocksum);
    scan_partials_kernel<<<1, 1024, 0, stream>>>(blocksum, nblocks, blockoff, rowp, n);
    write_scan_kernel<<<nblocks, 256, 0, stream>>>(deg, n, blockoff, rowp, cursor);
    fill_kernel<<<(e / 4 + 255) / 256, 256, 0, stream>>>(src, dst, e, cursor, esrc);

    int lb = (n + NPB - 1) / NPB;
    sage_layer_kernel<<<lb, 512, 0, stream>>>(x,  rowp, esrc, Wl,            Wr,            bb,          hA,  n, 1);
    sage_layer_kernel<<<lb, 512, 0, stream>>>(hA, rowp, esrc, Wl + 4096,     Wr + 4096,     bb + DD,     hB,  n, 1);
    sage_layer_kernel<<<lb, 512, 0, stream>>>(hB, rowp, esrc, Wl + 2 * 4096, Wr + 2 * 4096, bb + 2 * DD, out, n, 0);
}

// Round 9
// 342.413 us; speedup vs baseline: 2.5380x; 1.2872x over previous
//
#include <hip/hip_runtime.h>

#define DD 64
#define NPB 32       // nodes per block in sage_layer (512 threads, 16 lanes/node)
#define EPC 8192     // edges per chunk in binning
#define BK_SHIFT 9   // 512 nodes per bucket
#define BNODES 512

// ---- binned CSR build ----
// Pass A: per-chunk histogram over dst buckets -> histT[bucket][chunk]
__global__ __launch_bounds__(256) void binA_kernel(const int* __restrict__ dst, int e, int nc,
                                                   int* __restrict__ histT, int nbuck) {
    __shared__ int h[256];
    int tid = threadIdx.x, c = blockIdx.x;
    for (int i = tid; i < nbuck; i += 256) h[i] = 0;
    __syncthreads();
    int base = c * EPC;
#pragma unroll
    for (int j = 0; j < EPC / 256; ++j) {
        int i = base + j * 256 + tid;
        if (i < e) atomicAdd(&h[dst[i] >> BK_SHIFT], 1);
    }
    __syncthreads();
    for (int b = tid; b < nbuck; b += 256) histT[b * nc + c] = h[b];
}

// In-place exclusive scan over histT[0..tot) (single block)
__global__ __launch_bounds__(1024) void scanA_kernel(int* __restrict__ histT, int tot) {
    __shared__ int part[1024];
    int tid = threadIdx.x;
    int per = (tot + 1023) >> 10;
    int s0 = tid * per;
    int s1 = s0 + per; if (s1 > tot) s1 = tot;
    int s = 0;
    for (int i = s0; i < s1; ++i) s += histT[i];
    part[tid] = s;
    __syncthreads();
    for (int off = 1; off < 1024; off <<= 1) {
        int v = (tid >= off) ? part[tid - off] : 0;
        __syncthreads();
        part[tid] += v;
        __syncthreads();
    }
    int run = part[tid] - s;
    for (int i = s0; i < s1; ++i) { int v = histT[i]; histT[i] = run; run += v; }
}

// Pass B: scatter (src,dst) pairs into bucket-grouped runs (contiguous per chunk,bucket)
__global__ __launch_bounds__(256) void binB_kernel(const int* __restrict__ src, const int* __restrict__ dst,
                                                   int e, int nc, const int* __restrict__ offT,
                                                   int nbuck, int2* __restrict__ binned) {
    __shared__ int cur[256];
    int tid = threadIdx.x, c = blockIdx.x;
    for (int b = tid; b < nbuck; b += 256) cur[b] = offT[b * nc + c];
    __syncthreads();
    int base = c * EPC;
#pragma unroll
    for (int j = 0; j < EPC / 256; ++j) {
        int i = base + j * 256 + tid;
        if (i < e) {
            int d = dst[i];
            int p = atomicAdd(&cur[d >> BK_SHIFT], 1);
            binned[p] = make_int2(src[i], d);
        }
    }
}

// Per-bucket: degree hist -> LDS scan -> rowp (coalesced) -> place esrc in contiguous region
__global__ __launch_bounds__(BNODES) void place_kernel(const int2* __restrict__ binned,
                                                       const int* __restrict__ offT, int nc,
                                                       int nbuck, int e, int n,
                                                       int* __restrict__ rowp, int* __restrict__ esrc) {
    __shared__ int deg[BNODES];
    __shared__ int sc[BNODES];
    int tid = threadIdx.x, b = blockIdx.x;
    int node0 = b << BK_SHIFT;
    int base = offT[b * nc];
    int end  = (b + 1 < nbuck) ? offT[(b + 1) * nc] : e;
    deg[tid] = 0;
    __syncthreads();
    for (int i = base + tid; i < end; i += BNODES)
        atomicAdd(&deg[binned[i].y - node0], 1);
    __syncthreads();
    int v = deg[tid];
    sc[tid] = v;
    __syncthreads();
    for (int off = 1; off < BNODES; off <<= 1) {
        int t = (tid >= off) ? sc[tid - off] : 0;
        __syncthreads();
        sc[tid] += t;
        __syncthreads();
    }
    int excl = sc[tid] - v;
    int node = node0 + tid;
    if (node < n) rowp[node] = base + excl;
    if (b == 0 && tid == 0) rowp[n] = e;
    deg[tid] = base + excl;   // reuse as cursor
    __syncthreads();
    for (int i = base + tid; i < end; i += BNODES) {
        int2 p = binned[i];
        int pos = atomicAdd(&deg[p.y - node0], 1);
        esrc[pos] = p.x;
    }
}

// Fused layer: mean-aggregate (CSR gather, 4-deep MLP) then
// hout = agg @ Wl + hin @ Wr + b (+ optional relu).
// 512 threads = 32 nodes/block, 16 lanes/node, lane owns 4 output cols.
__global__ __launch_bounds__(512) void sage_layer_kernel(
    const float* __restrict__ hin, const int* __restrict__ rowp,
    const int* __restrict__ esrc,
    const float* __restrict__ Wl, const float* __restrict__ Wr,
    const float* __restrict__ bias, float* __restrict__ hout,
    int n, int relu)
{
    __shared__ float sWl[DD * DD];
    __shared__ float sWr[DD * DD];
    __shared__ float sB[DD];
    __shared__ float sAgg[NPB][68];
    __shared__ float sH[NPB][68];

    int tid = threadIdx.x;
    for (int i = tid; i < DD * DD / 4; i += 512) {
        reinterpret_cast<float4*>(sWl)[i] = reinterpret_cast<const float4*>(Wl)[i];
        reinterpret_cast<float4*>(sWr)[i] = reinterpret_cast<const float4*>(Wr)[i];
    }
    if (tid < DD) sB[tid] = bias[tid];
    __syncthreads();

    int grp = tid >> 4;
    int l   = tid & 15;
    int node = blockIdx.x * NPB + grp;
    if (node >= n) return;

    int beg = rowp[node], end = rowp[node + 1];
    float ax = 0.f, ay = 0.f, az = 0.f, aw = 0.f;
    int t = beg;
    for (; t + 4 <= end; t += 4) {
        int s0 = esrc[t + 0], s1 = esrc[t + 1], s2 = esrc[t + 2], s3 = esrc[t + 3];
        float4 v0 = *reinterpret_cast<const float4*>(hin + (size_t)s0 * DD + l * 4);
        float4 v1 = *reinterpret_cast<const float4*>(hin + (size_t)s1 * DD + l * 4);
        float4 v2 = *reinterpret_cast<const float4*>(hin + (size_t)s2 * DD + l * 4);
        float4 v3 = *reinterpret_cast<const float4*>(hin + (size_t)s3 * DD + l * 4);
        ax += (v0.x + v1.x) + (v2.x + v3.x);
        ay += (v0.y + v1.y) + (v2.y + v3.y);
        az += (v0.z + v1.z) + (v2.z + v3.z);
        aw += (v0.w + v1.w) + (v2.w + v3.w);
    }
    for (; t < end; ++t) {
        int s = esrc[t];
        float4 v = *reinterpret_cast<const float4*>(hin + (size_t)s * DD + l * 4);
        ax += v.x; ay += v.y; az += v.z; aw += v.w;
    }
    float cnt = fmaxf((float)(end - beg), 1.0f);
    ax /= cnt; ay /= cnt; az /= cnt; aw /= cnt;

    float4 h4 = *reinterpret_cast<const float4*>(hin + (size_t)node * DD + l * 4);
    *reinterpret_cast<float4*>(&sAgg[grp][l * 4]) = make_float4(ax, ay, az, aw);
    *reinterpret_cast<float4*>(&sH[grp][l * 4])   = h4;

    float o0 = sB[l * 4 + 0], o1 = sB[l * 4 + 1], o2 = sB[l * 4 + 2], o3 = sB[l * 4 + 3];
#pragma unroll 8
    for (int k = 0; k < DD; ++k) {
        float a = sAgg[grp][k];
        float h = sH[grp][k];
        float4 wl = *reinterpret_cast<const float4*>(&sWl[k * DD + l * 4]);
        float4 wr = *reinterpret_cast<const float4*>(&sWr[k * DD + l * 4]);
        o0 += a * wl.x + h * wr.x;
        o1 += a * wl.y + h * wr.y;
        o2 += a * wl.z + h * wr.z;
        o3 += a * wl.w + h * wr.w;
    }
    if (relu) {
        o0 = fmaxf(o0, 0.f); o1 = fmaxf(o1, 0.f);
        o2 = fmaxf(o2, 0.f); o3 = fmaxf(o3, 0.f);
    }
    *reinterpret_cast<float4*>(hout + (size_t)node * DD + l * 4) = make_float4(o0, o1, o2, o3);
}

extern "C" void kernel_launch(void* const* d_in, const int* in_sizes, int n_in,
                              void* d_out, int out_size, void* d_ws, size_t ws_size,
                              hipStream_t stream) {
    (void)n_in; (void)out_size; (void)ws_size;
    const float* x  = (const float*)d_in[0];
    const int*   ei = (const int*)d_in[1];
    const float* Wl = (const float*)d_in[2];
    const float* Wr = (const float*)d_in[3];
    const float* bb = (const float*)d_in[4];
    float* out = (float*)d_out;

    int n = in_sizes[0] / DD;   // 100000
    int e = in_sizes[1] / 2;    // 1600000
    const int* src = ei;
    const int* dst = ei + e;

    int nc    = (e + EPC - 1) / EPC;          // 196
    int nbuck = (n + BNODES - 1) >> BK_SHIFT; // 196

    char* cur = (char*)d_ws;
    auto alloc = [&](size_t bytes) -> void* {
        void* p = (void*)cur;
        cur += (bytes + 255) & ~(size_t)255;
        return p;
    };
    int*   histT  = (int*)alloc((size_t)nbuck * nc * 4);
    int2*  binned = (int2*)alloc((size_t)e * 8);
    int*   rowp   = (int*)alloc(((size_t)n + 1) * 4);
    int*   esrc   = (int*)alloc((size_t)e * 4);
    float* hA     = (float*)alloc((size_t)n * DD * 4);
    float* hB     = (float*)alloc((size_t)n * DD * 4);

    binA_kernel<<<nc, 256, 0, stream>>>(dst, e, nc, histT, nbuck);
    scanA_kernel<<<1, 1024, 0, stream>>>(histT, nbuck * nc);
    binB_kernel<<<nc, 256, 0, stream>>>(src, dst, e, nc, histT, nbuck, binned);
    place_kernel<<<nbuck, BNODES, 0, stream>>>(binned, histT, nc, nbuck, e, n, rowp, esrc);

    int lb = (n + NPB - 1) / NPB;
    sage_layer_kernel<<<lb, 512, 0, stream>>>(x,  rowp, esrc, Wl,            Wr,            bb,          hA,  n, 1);
    sage_layer_kernel<<<lb, 512, 0, stream>>>(hA, rowp, esrc, Wl + 4096,     Wr + 4096,     bb + DD,     hB,  n, 1);
    sage_layer_kernel<<<lb, 512, 0, stream>>>(hB, rowp, esrc, Wl + 2 * 4096, Wr + 2 * 4096, bb + 2 * DD, out, n, 0);
}